// Round 1
// baseline (4659.229 us; speedup 1.0000x reference)
//
#include <hip/hip_runtime.h>
#include <stdint.h>

// GRU acoustic model, fp32 I/O. R10: pipeline x-staging off the critical
// path + slim swizzled hbuf. R9 post-mortem: per active CU MfmaUtil ~28%,
// VALU ~37%, ~35% idle. Two serial sinks: (a) wave-3 global x load drained
// by __syncthreads' vmcnt(0) before B1 every step (~500-900 cyc HBM
// latency on the step critical path); (b) A-fragment ds_read_b128 reads
// 16 rows (12 of them zero) on an 8-bank stride (SQ_LDS_BANK_CONFLICT
// 12.6M). Changes: raw lgkm-only barriers (no vmcnt drain); x loaded one
// step ahead by wave 7 and written to xt AFTER the epilogue (2-step
// vmcnt slack); hbuf -> [2][4][320] XOR-swizzled (byte ^= row<<4, 2-way
// max) with a shared zero granule broadcast for the 48 nl>=4 lanes;
// epilogue remapped lane->(row, 4 consecutive cols): float4 scr reads,
// one packed dword h-write, waves 5-7 skip wave-uniformly. Decoder
// unchanged (proven R2-R9).
#define FEAT 13
#define EMB 300
#define BATCH 64
#define TSTEPS 2048
#define ROWS 4              // valid batch rows per WG
#define NCOL 304            // 19 slices x 16 gate cols (300 + 4 pad)
#define HSTR 320            // hbuf row stride, bytes (20 granules of 16)
#define QW  2199.7045f      // 127*sqrt(300)
#define SWH 3.5795795e-6f   // 1/(127*127*sqrt(300))

typedef float  floatx4 __attribute__((ext_vector_type(4)));
typedef short  shortx8 __attribute__((ext_vector_type(8)));
typedef int    intx4   __attribute__((ext_vector_type(4)));

__device__ __forceinline__ uint16_t f2b(float f) {
  union { float f; uint32_t i; } c; c.f = f;
  uint32_t r = c.i + 0x7fffu + ((c.i >> 16) & 1u);
  return (uint16_t)(r >> 16);
}
__device__ __forceinline__ float sigf(float x) {
  return __builtin_amdgcn_rcpf(1.f + __expf(-x));
}
__device__ __forceinline__ float tanhf_(float x) {
  return 1.f - 2.f * __builtin_amdgcn_rcpf(1.f + __expf(2.f * x));
}
__device__ __forceinline__ int q8w(float v) {
  return __float2int_rn(fminf(fmaxf(v * QW, -127.f), 127.f));
}

// Raw barrier: LDS-order only. Does NOT drain vmcnt, so wave 7's
// in-flight global x loads float across it (the whole point).
__device__ __forceinline__ void barx() {
  asm volatile("s_waitcnt lgkmcnt(0)" ::: "memory");
  __builtin_amdgcn_s_barrier();
  asm volatile("" ::: "memory");
}

#define MFI8(A, B, C) __builtin_amdgcn_mfma_i32_16x16x64_i8(A, B, C, 0, 0, 0)
#define MFBF(A, B, C) __builtin_amdgcn_mfma_f32_16x16x32_bf16(A, B, C, 0, 0, 0)

__launch_bounds__(512, 2)
__global__ void gru_enc(const float* __restrict__ x,     // [64][2048][13]
                        const float* __restrict__ eWih,  // [900][13]
                        const float* __restrict__ eWhh,  // [900][300]
                        const float* __restrict__ ebih,  // [900]
                        const float* __restrict__ ebhh,  // [900]
                        const float* __restrict__ fcW,   // [300][300]
                        const float* __restrict__ fcb,   // [300]
                        float* __restrict__ out) {
  // hb: element (row r, col c) lives at byte r*HSTR + (c ^ (r<<4)).
  // XOR toggles the 16B granule index (bits 4-5 for r<4), giving <=2-way
  // banks for the 16 real A-read lanes; logical K pad 304-319 maps to
  // granules never written after zero-init -> reads return 0.
  __shared__ __align__(16) signed char hb[2][ROWS][HSTR];     // 2560 B
  __shared__ __align__(16) signed char zsh[16];               // zero granule
  __shared__ __align__(16) uint16_t    xt[2][16][32];         // 2048 B
  __shared__ __align__(16) float       scr[4][ROWS][NCOL];    // 19456 B
  __shared__ __align__(16) signed char wl56[5][1024];         // 5120 B
  __shared__ __align__(16) uint16_t    wx56[64][8];           // 1024 B

  const int tid = threadIdx.x, lane = tid & 63, w = tid >> 6;
  const int nl = lane & 15, q = lane >> 4;
  const int g = blockIdx.x;          // batch rows 4g..4g+3

  // ---- one-time: 7 register gate-blocks per wave (block b=7w+k) ----
  intx4   Bh[7][5];
  shortx8 Bx[7];
  float   bA[7], bB[7];
#pragma unroll
  for (int k = 0; k < 7; ++k) {
    int b = 7 * w + k, s = b / 3, gt = b - 3 * s;
    int jj = 16 * s + nl;
    bool jvv = (jj < EMB);
    int R = gt * EMB + (jvv ? jj : 0);
    for (int kt = 0; kt < 5; ++kt) {
      int bb[4] = {0, 0, 0, 0};
      for (int e = 0; e < 16; ++e) {
        int kk = kt * 64 + q * 16 + e;
        float v = (jvv && kk < EMB) ? eWhh[(size_t)R * EMB + kk] : 0.f;
        bb[e >> 2] |= (q8w(v) & 255) << ((e & 3) * 8);
      }
      intx4 t4; t4[0] = bb[0]; t4[1] = bb[1]; t4[2] = bb[2]; t4[3] = bb[3];
      Bh[k][kt] = t4;
    }
    union { uint16_t u[8]; shortx8 v; } c;
    for (int e = 0; e < 8; ++e) {
      int kk = q * 8 + e;
      c.u[e] = (jvv && kk < FEAT) ? f2b(eWih[R * FEAT + kk]) : (uint16_t)0;
    }
    Bx[k] = c.v;
    if (gt == 2) {
      bA[k] = jvv ? ebhh[2 * EMB + jj] : 0.f;   // hn bias
      bB[k] = jvv ? ebih[2 * EMB + jj] : 0.f;   // in bias
    } else {
      bA[k] = jvv ? (ebih[gt * EMB + jj] + ebhh[gt * EMB + jj]) : 0.f;
      bB[k] = 0.f;
    }
  }
  // block 56 (slice 18, n-gate) -> LDS, processed by wave 0
  float b56A = 0.f, b56B = 0.f;
  if (w == 0) {
    int jj = 288 + nl;
    bool jvv = (jj < EMB);
    int R = 2 * EMB + (jvv ? jj : 0);
    for (int kt = 0; kt < 5; ++kt)
      for (int e = 0; e < 16; ++e) {
        int kk = kt * 64 + q * 16 + e;
        float v = (jvv && kk < EMB) ? eWhh[(size_t)R * EMB + kk] : 0.f;
        wl56[kt][lane * 16 + e] = (signed char)q8w(v);
      }
    for (int e = 0; e < 8; ++e) {
      int kk = q * 8 + e;
      wx56[lane][e] = (jvv && kk < FEAT) ? f2b(eWih[R * FEAT + kk]) : (uint16_t)0;
    }
    b56A = jvv ? ebhh[2 * EMB + jj] : 0.f;
    b56B = jvv ? ebih[2 * EMB + jj] : 0.f;
  }

  // ---- init LDS: zero h/x buffers + zero granule, then stage x_0 ----
  for (int i = tid; i < 2 * ROWS * HSTR; i += 512) ((signed char*)hb)[i] = 0;
  if (tid < 16) zsh[tid] = 0;
  for (int i = tid; i < 2 * 16 * 32; i += 512) ((uint16_t*)xt)[i] = 0;
  __syncthreads();
  if (tid < ROWS * FEAT) {
    int m = tid / FEAT, f = tid - m * FEAT;
    xt[0][m][f] = f2b(x[((size_t)(g * ROWS + m) * TSTEPS) * FEAT + f]);
  }
  __syncthreads();

  // ---- x prefetch pipeline (wave 7: epilogue-idle) ----
  const bool xl = (w == 7) && (lane < ROWS * FEAT);
  const int xm = lane / FEAT, xf = lane - xm * FEAT;
  const float* xbase = x + ((size_t)(g * ROWS + xm) * TSTEPS) * FEAT + xf;
  float xcur = 0.f;                      // holds x_t for bottom of iter t
  if (xl) xcur = xbase[FEAT];            // x_1
  const float* xnq = xbase + 2 * FEAT;   // next load: x_2

  float hprev[4] = {0.f, 0.f, 0.f, 0.f};  // lane's 4 cols of one row
  const int eqd = tid >> 2, erow = tid & 3;

  // ================= recurrence: 2 lgkm-only barriers/step =================
  for (int t = 1; t <= TSTEPS; ++t) {
    const int p = (t - 1) & 1, pn = t & 1;

    // issue next x load (no wait here; consumed bottom of NEXT iter)
    float xnxt = 0.f;
    if (xl && t < TSTEPS - 1) { xnxt = *xnq; xnq += FEAT; }

    // A fragments: 16 real lanes (nl<4) swizzled; 48 lanes broadcast zero
    const signed char* hbp = &hb[p][0][0];
    intx4 Ah[5];
#pragma unroll
    for (int kt = 0; kt < 5; ++kt) {
      const int o = kt * 64 + q * 16;
      const signed char* ap =
          (nl < ROWS) ? (hbp + nl * HSTR + (o ^ (nl << 4))) : zsh;
      Ah[kt] = *(const intx4*)ap;
    }
    shortx8 Ax = *(const shortx8*)&xt[p][nl][q * 8];

    // MFMA per block -> pre-activations(+bias) into scr (valid rows q==0)
#pragma unroll
    for (int k = 0; k < 7; ++k) {
      int b = 7 * w + k, s = b / 3, gt = b - 3 * s;
      intx4 ai = {0, 0, 0, 0};
#pragma unroll
      for (int kt = 0; kt < 5; ++kt) ai = MFI8(Ah[kt], Bh[k][kt], ai);
      floatx4 ax = {0.f, 0.f, 0.f, 0.f};
      ax = MFBF(Ax, Bx[k], ax);
      if (q == 0) {
        int jj = 16 * s + nl;
        if (gt == 2) {
#pragma unroll
          for (int i = 0; i < 4; ++i) {
            scr[2][i][jj] = (float)ai[i] * SWH + bA[k];
            scr[3][i][jj] = ax[i] + bB[k];
          }
        } else {
#pragma unroll
          for (int i = 0; i < 4; ++i)
            scr[gt][i][jj] = (float)ai[i] * SWH + ax[i] + bA[k];
        }
      }
    }
    if (w == 0) {   // block 56 from LDS
      intx4 ai = {0, 0, 0, 0};
#pragma unroll
      for (int kt = 0; kt < 5; ++kt) {
        intx4 bb = *(const intx4*)&wl56[kt][lane * 16];
        ai = MFI8(Ah[kt], bb, ai);
      }
      shortx8 bx = *(const shortx8*)&wx56[lane][0];
      floatx4 ax = {0.f, 0.f, 0.f, 0.f};
      ax = MFBF(Ax, bx, ax);
      if (q == 0) {
        int jj = 288 + nl;
#pragma unroll
        for (int i = 0; i < 4; ++i) {
          scr[2][i][jj] = (float)ai[i] * SWH + b56A;
          scr[3][i][jj] = ax[i] + b56B;
        }
      }
    }
    barx();   // B1: scr complete (lgkm only -- x loads stay in flight)

    // epilogue: lane owns (row erow, cols 4*eqd..+3); waves 5-7 skip
    if (tid < ROWS * 76) {   // 304 active lanes, wave-uniform for w>=5
      const int c0 = eqd << 2;
      floatx4 prv = *(const floatx4*)&scr[0][erow][c0];
      floatx4 pzv = *(const floatx4*)&scr[1][erow][c0];
      floatx4 phv = *(const floatx4*)&scr[2][erow][c0];
      floatx4 piv = *(const floatx4*)&scr[3][erow][c0];
      uint32_t packed = 0;
#pragma unroll
      for (int j = 0; j < 4; ++j) {
        float r = sigf(prv[j]), z = sigf(pzv[j]);
        float n = tanhf_(piv[j] + r * phv[j]);
        float h = z * (hprev[j] - n) + n;
        hprev[j] = h;
        float hq = fminf(fmaxf(h * 127.f, -127.f), 127.f);
        packed |= ((uint32_t)(uint8_t)(signed char)__float2int_rn(hq))
                  << (8 * j);
      }
      *(uint32_t*)(&hb[pn][erow][0] + (c0 ^ (erow << 4))) = packed;
    }
    // wave 7: stage x_t (loaded last iter -> ~2 steps of vmcnt slack)
    if (xl && t < TSTEPS) xt[pn][xm][xf] = f2b(xcur);

    barx();   // B2: h_t + x_t complete
    xcur = xnxt;
  }

  // ================= fc: emb = relu(h_T @ fcW^T + fcb) =================
  {
    float* oemb = out + (size_t)BATCH * TSTEPS * FEAT;
    intx4 AhT[5];
#pragma unroll
    for (int kt = 0; kt < 5; ++kt) {  // T even -> final h in hb[0]
      const int o = kt * 64 + q * 16;
      const signed char* ap =
          (nl < ROWS) ? (&hb[0][0][0] + nl * HSTR + (o ^ (nl << 4))) : zsh;
      AhT[kt] = *(const intx4*)ap;
    }
    for (int u = 0; u < 3; ++u) {
      int s = w + u * 8;
      if (s >= 19) break;     // wave-uniform
      int jj = 16 * s + nl;
      bool jvv = (jj < EMB);
      intx4 acc = {0, 0, 0, 0};
      for (int kt = 0; kt < 5; ++kt) {
        int bb[4] = {0, 0, 0, 0};
        for (int e = 0; e < 16; ++e) {
          int kk = kt * 64 + q * 16 + e;
          float v = (jvv && kk < EMB) ? fcW[(size_t)jj * EMB + kk] : 0.f;
          bb[e >> 2] |= (q8w(v) & 255) << ((e & 3) * 8);
        }
        intx4 b4; b4[0] = bb[0]; b4[1] = bb[1]; b4[2] = bb[2]; b4[3] = bb[3];
        acc = MFI8(AhT[kt], b4, acc);
      }
      if (q == 0 && jvv) {
        float fb = fcb[jj];
#pragma unroll
        for (int i = 0; i < 4; ++i) {
          float e2 = (float)acc[i] * SWH + fb;
          oemb[(size_t)(g * ROWS + i) * EMB + jj] = e2 > 0.f ? e2 : 0.f;
        }
      }
    }
  }
}

// ---------------- decoder: 1 wave per batch, all fp32 (proven) --------------
__launch_bounds__(64, 1)
__global__ void gru_dec(const float* __restrict__ dWih,  // [39][300]
                        const float* __restrict__ dWhh,  // [39][13]
                        const float* __restrict__ dbih,  // [39]
                        const float* __restrict__ dbhh,  // [39]
                        float* __restrict__ out) {
  const int b  = blockIdx.x;
  const int lj = threadIdx.x;            // [0,13)=r [13,26)=z [26,39)=n
  const float* emb = out + (size_t)BATCH * TSTEPS * FEAT + (size_t)b * EMB;

  float Wd[FEAT];
#pragma unroll
  for (int k = 0; k < FEAT; ++k) Wd[k] = 0.f;
  float bhhv = 0.f, dgi = 0.f;
  if (lj < 3 * FEAT) {
#pragma unroll
    for (int k = 0; k < FEAT; ++k) Wd[k] = dWhh[lj * FEAT + k];
    bhhv = dbhh[lj];
    dgi  = dbih[lj];
#pragma unroll 4
    for (int k = 0; k < EMB; ++k)
      dgi = fmaf(emb[k], dWih[lj * EMB + k], dgi);
  }

  float hrep[FEAT];
#pragma unroll
  for (int k = 0; k < FEAT; ++k) hrep[k] = 0.f;
  float hown = 0.f;
  const bool nlane = (lj >= 2 * FEAT && lj < 3 * FEAT);
  float* orow = out + (size_t)b * TSTEPS * FEAT;

  for (int t = 0; t < TSTEPS; ++t) {
    float gh = bhhv;
#pragma unroll
    for (int k = 0; k < FEAT; ++k) gh = fmaf(Wd[k], hrep[k], gh);
    float sg = sigf(dgi + gh);
    float rr = __shfl(sg, (lj - 2 * FEAT) & 63);
    float zz = __shfl(sg, (lj - FEAT) & 63);
    float nn = tanhf_(dgi + rr * gh);
    float hn = zz * (hown - nn) + nn;
    bool same = (!nlane) || (hn == hown);
    if (nlane) {
      orow[t * FEAT + (lj - 2 * FEAT)] = hn;
      hown = hn;
    }
#pragma unroll
    for (int k = 0; k < FEAT; ++k) hrep[k] = __shfl(hown, 2 * FEAT + k);
    if (__all(same)) {  // exact fp32 fixed point -> rest constant
      if (nlane) {
        for (int t2 = t + 1; t2 < TSTEPS; ++t2)
          orow[t2 * FEAT + (lj - 2 * FEAT)] = hn;
      }
      break;
    }
  }
}

extern "C" void kernel_launch(void* const* d_in, const int* in_sizes, int n_in,
                              void* d_out, int out_size, void* d_ws, size_t ws_size,
                              hipStream_t stream) {
  (void)in_sizes; (void)n_in; (void)out_size; (void)d_ws; (void)ws_size;
  const float* x    = (const float*)d_in[0];
  const float* eWih = (const float*)d_in[1];
  const float* eWhh = (const float*)d_in[2];
  const float* ebih = (const float*)d_in[3];
  const float* ebhh = (const float*)d_in[4];
  const float* fcW  = (const float*)d_in[5];
  const float* fcb  = (const float*)d_in[6];
  const float* dWih = (const float*)d_in[7];
  const float* dWhh = (const float*)d_in[8];
  const float* dbih = (const float*)d_in[9];
  const float* dbhh = (const float*)d_in[10];

  hipLaunchKernelGGL(gru_enc, dim3(BATCH / ROWS), dim3(512), 0, stream,
                     x, eWih, eWhh, ebih, ebhh, fcW, fcb, (float*)d_out);
  hipLaunchKernelGGL(gru_dec, dim3(BATCH), dim3(64), 0, stream,
                     dWih, dWhh, dbih, dbhh, (float*)d_out);
}

// Round 2
// 3400.997 us; speedup vs baseline: 1.3700x; 1.3700x over previous
//
#include <hip/hip_runtime.h>
#include <stdint.h>

// GRU acoustic model, fp32 I/O. R11: single-barrier step — kill scr + B1.
// R10 post-mortem: bank-conflict fix (12.6M->2.4M) and vmcnt-drain removal
// did NOT help; epilogue serial depth (3->4) regressed it. The step is
// phase-structure-bound: MFMA issue is only ~1800 of 4570 cyc; the scr
// round-trip (write preact -> B1 -> read -> trans -> write h -> B2) is the
// rest. R11 restructures so gates colocate in the owning wave:
//  (1) slice-complete assignment: wave w owns slices {w, w+8} in registers
//      (all 3 gates), waves 0-2 additionally own slices 16-18 with B in LDS.
//  (2) row-scattered A: batch row r at MFMA row 4r -> C reg 0 of EVERY lane
//      holds one valid (row q, col 16s+nl) output. Gate math (2 sig + tanh)
//      runs in-register, 1 elem/slice/lane, h written as 1 byte to swizzled
//      hb. One lgkm-barrier per step. Numerically identical to R9/R10.
// x pipelined by wave 7 (loaded a step ahead, staged before barrier).
// Decoder unchanged (proven R2-R10).
#define FEAT 13
#define EMB 300
#define BATCH 64
#define TSTEPS 2048
#define ROWS 4              // valid batch rows per WG
#define HSTR 320            // hbuf row stride, bytes (20 granules of 16)
#define QW  2199.7045f      // 127*sqrt(300)
#define SWH 3.5795795e-6f   // 1/(127*127*sqrt(300))

typedef float  floatx4 __attribute__((ext_vector_type(4)));
typedef short  shortx8 __attribute__((ext_vector_type(8)));
typedef int    intx4   __attribute__((ext_vector_type(4)));

__device__ __forceinline__ uint16_t f2b(float f) {
  union { float f; uint32_t i; } c; c.f = f;
  uint32_t r = c.i + 0x7fffu + ((c.i >> 16) & 1u);
  return (uint16_t)(r >> 16);
}
__device__ __forceinline__ float sigf(float x) {
  return __builtin_amdgcn_rcpf(1.f + __expf(-x));
}
__device__ __forceinline__ float tanhf_(float x) {
  return 1.f - 2.f * __builtin_amdgcn_rcpf(1.f + __expf(2.f * x));
}
__device__ __forceinline__ int q8w(float v) {
  return __float2int_rn(fminf(fmaxf(v * QW, -127.f), 127.f));
}

// Raw barrier: LDS-order only (no vmcnt drain; wave 7's global x loads
// stay in flight across it).
__device__ __forceinline__ void barx() {
  asm volatile("s_waitcnt lgkmcnt(0)" ::: "memory");
  __builtin_amdgcn_s_barrier();
  asm volatile("" ::: "memory");
}

#define MFI8(A, B, C) __builtin_amdgcn_mfma_i32_16x16x64_i8(A, B, C, 0, 0, 0)
#define MFBF(A, B, C) __builtin_amdgcn_mfma_f32_16x16x32_bf16(A, B, C, 0, 0, 0)

__launch_bounds__(512, 2)
__global__ void gru_enc(const float* __restrict__ x,     // [64][2048][13]
                        const float* __restrict__ eWih,  // [900][13]
                        const float* __restrict__ eWhh,  // [900][300]
                        const float* __restrict__ ebih,  // [900]
                        const float* __restrict__ ebhh,  // [900]
                        const float* __restrict__ fcW,   // [300][300]
                        const float* __restrict__ fcb,   // [300]
                        float* __restrict__ out) {
  // hb: element (row r, col c) at byte r*HSTR + (c ^ (r<<4)) (involution;
  // granule index (c>>4)^r stays < 20). Unwritten granules remain zero.
  __shared__ __align__(16) signed char hb[2][ROWS][HSTR];     // 2560 B
  __shared__ __align__(16) signed char zsh[16];               // zero granule
  __shared__ __align__(16) uint16_t    xt[2][16][32];         // 2048 B
  __shared__ __align__(16) signed char wlB[3][3][5][1024];    // 46080 B

  const int tid = threadIdx.x, lane = tid & 63, w = tid >> 6;
  const int nl = lane & 15, q = lane >> 4;
  const int g = blockIdx.x;          // batch rows 4g..4g+3

  // ---- 2 register slices per wave: s = w, w+8 (slices 0..15) ----
  intx4   Bh[2][3][5];
  shortx8 Bx[2][3];
  float   bS0[2], bS1[2], bHN[2], bIN[2];
#pragma unroll
  for (int si = 0; si < 2; ++si) {
    const int s = w + 8 * si;
    const int jj = 16 * s + nl;            // < 271 < EMB: always valid
#pragma unroll
    for (int gt = 0; gt < 3; ++gt) {
      const int R = gt * EMB + jj;
      for (int kt = 0; kt < 5; ++kt) {
        int bb[4] = {0, 0, 0, 0};
        for (int e = 0; e < 16; ++e) {
          int kk = kt * 64 + q * 16 + e;
          float v = (kk < EMB) ? eWhh[(size_t)R * EMB + kk] : 0.f;
          bb[e >> 2] |= (q8w(v) & 255) << ((e & 3) * 8);
        }
        intx4 t4; t4[0] = bb[0]; t4[1] = bb[1]; t4[2] = bb[2]; t4[3] = bb[3];
        Bh[si][gt][kt] = t4;
      }
      union { uint16_t u[8]; shortx8 v; } c;
      for (int e = 0; e < 8; ++e) {
        int kk = q * 8 + e;
        c.u[e] = (kk < FEAT) ? f2b(eWih[R * FEAT + kk]) : (uint16_t)0;
      }
      Bx[si][gt] = c.v;
    }
    bS0[si] = ebih[jj] + ebhh[jj];
    bS1[si] = ebih[EMB + jj] + ebhh[EMB + jj];
    bHN[si] = ebhh[2 * EMB + jj];
    bIN[si] = ebih[2 * EMB + jj];
  }
  // ---- extra slices 16..18 -> waves 0..2: Bh in LDS, Bx/bias in regs ----
  shortx8 BxE[3];
  float bS0E = 0.f, bS1E = 0.f, bHNE = 0.f, bINE = 0.f;
  if (w < 3) {
    const int s = 16 + w;
    const int jj = 16 * s + nl;
    const bool jvv = (jj < EMB);
    const int J = jvv ? jj : 0;
#pragma unroll
    for (int gt = 0; gt < 3; ++gt) {
      const int R = gt * EMB + J;
      for (int kt = 0; kt < 5; ++kt)
        for (int e = 0; e < 16; ++e) {
          int kk = kt * 64 + q * 16 + e;
          float v = (jvv && kk < EMB) ? eWhh[(size_t)R * EMB + kk] : 0.f;
          wlB[w][gt][kt][lane * 16 + e] = (signed char)q8w(v);
        }
      union { uint16_t u[8]; shortx8 v; } c;
      for (int e = 0; e < 8; ++e) {
        int kk = q * 8 + e;
        c.u[e] = (jvv && kk < FEAT) ? f2b(eWih[R * FEAT + kk]) : (uint16_t)0;
      }
      BxE[gt] = c.v;
    }
    bS0E = jvv ? (ebih[jj] + ebhh[jj]) : 0.f;
    bS1E = jvv ? (ebih[EMB + jj] + ebhh[EMB + jj]) : 0.f;
    bHNE = jvv ? ebhh[2 * EMB + jj] : 0.f;
    bINE = jvv ? ebih[2 * EMB + jj] : 0.f;
  }

  // ---- init LDS: zero h/x buffers + zero granule, then stage x_0 ----
  for (int i = tid; i < 2 * ROWS * HSTR; i += 512) ((signed char*)hb)[i] = 0;
  if (tid < 16) zsh[tid] = 0;
  for (int i = tid; i < 2 * 16 * 32; i += 512) ((uint16_t*)xt)[i] = 0;
  __syncthreads();
  if (tid < ROWS * FEAT) {
    int m = tid / FEAT, f = tid - m * FEAT;
    xt[0][4 * m][f] = f2b(x[((size_t)(g * ROWS + m) * TSTEPS) * FEAT + f]);
  }
  __syncthreads();

  // ---- x prefetch pipeline (wave 7) ----
  const bool xl = (w == 7) && (lane < ROWS * FEAT);
  const int xm = lane / FEAT, xf = lane - xm * FEAT;
  const float* xbase = x + ((size_t)(g * ROWS + xm) * TSTEPS) * FEAT + xf;
  float xcur = 0.f;                      // x_t, staged bottom of iter t
  if (xl) xcur = xbase[FEAT];            // x_1
  const float* xnq = xbase + 2 * FEAT;   // next load: x_2

  float hprev[3] = {0.f, 0.f, 0.f};      // lane's h for its 2-3 slices
  const int rr_ = nl >> 2;               // A-side batch row (if nl%4==0)
  const bool areal = ((nl & 3) == 0);

  // ================= recurrence: ONE lgkm barrier/step =================
  for (int t = 1; t <= TSTEPS; ++t) {
    const int p = (t - 1) & 1, pn = t & 1;
    float xnxt = 0.f;
    if (xl && t < TSTEPS - 1) { xnxt = *xnq; xnq += FEAT; }

    // A fragments: batch row r at MFMA row 4r; other rows broadcast zero
    const signed char* hbp = &hb[p][0][0];
    intx4 Ah[5];
#pragma unroll
    for (int kt = 0; kt < 5; ++kt) {
      const int o = kt * 64 + q * 16;
      const signed char* ap =
          areal ? (hbp + rr_ * HSTR + (o ^ (rr_ << 4))) : zsh;
      Ah[kt] = *(const intx4*)ap;
    }
    const shortx8 Ax = *(const shortx8*)&xt[p][nl][q * 8];

    signed char* hwb = &hb[pn][q][0];
    const int wsw = q << 4;

#pragma unroll
    for (int si = 0; si < 2; ++si) {
      intx4 aR = {0, 0, 0, 0}, aZ = {0, 0, 0, 0}, aN = {0, 0, 0, 0};
#pragma unroll
      for (int kt = 0; kt < 5; ++kt) {
        aR = MFI8(Ah[kt], Bh[si][0][kt], aR);
        aZ = MFI8(Ah[kt], Bh[si][1][kt], aZ);
        aN = MFI8(Ah[kt], Bh[si][2][kt], aN);
      }
      floatx4 z4 = {0.f, 0.f, 0.f, 0.f};
      floatx4 xR = MFBF(Ax, Bx[si][0], z4);
      floatx4 xZ = MFBF(Ax, Bx[si][1], z4);
      floatx4 xN = MFBF(Ax, Bx[si][2], z4);
      // reg 0 = (batch row q, col 16s+nl) — gates fully in-register
      float r  = sigf((float)aR[0] * SWH + xR[0] + bS0[si]);
      float z  = sigf((float)aZ[0] * SWH + xZ[0] + bS1[si]);
      float hn = (float)aN[0] * SWH + bHN[si];
      float n  = tanhf_(xN[0] + bIN[si] + r * hn);
      float h  = z * (hprev[si] - n) + n;
      hprev[si] = h;
      float hq = fminf(fmaxf(h * 127.f, -127.f), 127.f);
      const int c = 16 * (w + 8 * si) + nl;
      hwb[c ^ wsw] = (signed char)__float2int_rn(hq);
    }
    if (w < 3) {   // extra slice 16+w, B from LDS
      intx4 aR = {0, 0, 0, 0}, aZ = {0, 0, 0, 0}, aN = {0, 0, 0, 0};
#pragma unroll
      for (int kt = 0; kt < 5; ++kt) {
        const intx4 bR = *(const intx4*)&wlB[w][0][kt][lane * 16];
        const intx4 bZ = *(const intx4*)&wlB[w][1][kt][lane * 16];
        const intx4 bN = *(const intx4*)&wlB[w][2][kt][lane * 16];
        aR = MFI8(Ah[kt], bR, aR);
        aZ = MFI8(Ah[kt], bZ, aZ);
        aN = MFI8(Ah[kt], bN, aN);
      }
      floatx4 z4 = {0.f, 0.f, 0.f, 0.f};
      floatx4 xR = MFBF(Ax, BxE[0], z4);
      floatx4 xZ = MFBF(Ax, BxE[1], z4);
      floatx4 xN = MFBF(Ax, BxE[2], z4);
      float r  = sigf((float)aR[0] * SWH + xR[0] + bS0E);
      float z  = sigf((float)aZ[0] * SWH + xZ[0] + bS1E);
      float hn = (float)aN[0] * SWH + bHNE;
      float n  = tanhf_(xN[0] + bINE + r * hn);
      float h  = z * (hprev[2] - n) + n;
      hprev[2] = h;
      float hq = fminf(fmaxf(h * 127.f, -127.f), 127.f);
      const int c = 16 * (16 + w) + nl;
      hwb[c ^ wsw] = (signed char)__float2int_rn(hq);
    }
    // wave 7: stage x_t (loaded last iter -> a full step of vmcnt slack)
    if (xl && t < TSTEPS) xt[pn][4 * xm][xf] = f2b(xcur);

    barx();   // h_t + x_t visible; hb[p]/hb[pn] double-buffered
    xcur = xnxt;
  }

  // ================= fc: emb = relu(h_T @ fcW^T + fcb) =================
  {
    float* oemb = out + (size_t)BATCH * TSTEPS * FEAT;
    intx4 AhT[5];
#pragma unroll
    for (int kt = 0; kt < 5; ++kt) {  // T even -> final h in hb[0]
      const int o = kt * 64 + q * 16;
      const signed char* ap =
          areal ? (&hb[0][0][0] + rr_ * HSTR + (o ^ (rr_ << 4))) : zsh;
      AhT[kt] = *(const intx4*)ap;
    }
    for (int u = 0; u < 3; ++u) {
      int s = w + u * 8;
      if (s >= 19) break;     // wave-uniform
      int jj = 16 * s + nl;
      bool jvv = (jj < EMB);
      intx4 acc = {0, 0, 0, 0};
      for (int kt = 0; kt < 5; ++kt) {
        int bb[4] = {0, 0, 0, 0};
        for (int e = 0; e < 16; ++e) {
          int kk = kt * 64 + q * 16 + e;
          float v = (jvv && kk < EMB) ? fcW[(size_t)jj * EMB + kk] : 0.f;
          bb[e >> 2] |= (q8w(v) & 255) << ((e & 3) * 8);
        }
        intx4 b4; b4[0] = bb[0]; b4[1] = bb[1]; b4[2] = bb[2]; b4[3] = bb[3];
        acc = MFI8(AhT[kt], b4, acc);
      }
      if (jvv) {  // reg 0 = (batch row q, col jj)
        float e2 = (float)acc[0] * SWH + fcb[jj];
        oemb[(size_t)(g * ROWS + q) * EMB + jj] = e2 > 0.f ? e2 : 0.f;
      }
    }
  }
}

// ---------------- decoder: 1 wave per batch, all fp32 (proven) --------------
__launch_bounds__(64, 1)
__global__ void gru_dec(const float* __restrict__ dWih,  // [39][300]
                        const float* __restrict__ dWhh,  // [39][13]
                        const float* __restrict__ dbih,  // [39]
                        const float* __restrict__ dbhh,  // [39]
                        float* __restrict__ out) {
  const int b  = blockIdx.x;
  const int lj = threadIdx.x;            // [0,13)=r [13,26)=z [26,39)=n
  const float* emb = out + (size_t)BATCH * TSTEPS * FEAT + (size_t)b * EMB;

  float Wd[FEAT];
#pragma unroll
  for (int k = 0; k < FEAT; ++k) Wd[k] = 0.f;
  float bhhv = 0.f, dgi = 0.f;
  if (lj < 3 * FEAT) {
#pragma unroll
    for (int k = 0; k < FEAT; ++k) Wd[k] = dWhh[lj * FEAT + k];
    bhhv = dbhh[lj];
    dgi  = dbih[lj];
#pragma unroll 4
    for (int k = 0; k < EMB; ++k)
      dgi = fmaf(emb[k], dWih[lj * EMB + k], dgi);
  }

  float hrep[FEAT];
#pragma unroll
  for (int k = 0; k < FEAT; ++k) hrep[k] = 0.f;
  float hown = 0.f;
  const bool nlane = (lj >= 2 * FEAT && lj < 3 * FEAT);
  float* orow = out + (size_t)b * TSTEPS * FEAT;

  for (int t = 0; t < TSTEPS; ++t) {
    float gh = bhhv;
#pragma unroll
    for (int k = 0; k < FEAT; ++k) gh = fmaf(Wd[k], hrep[k], gh);
    float sg = sigf(dgi + gh);
    float rr = __shfl(sg, (lj - 2 * FEAT) & 63);
    float zz = __shfl(sg, (lj - FEAT) & 63);
    float nn = tanhf_(dgi + rr * gh);
    float hn = zz * (hown - nn) + nn;
    bool same = (!nlane) || (hn == hown);
    if (nlane) {
      orow[t * FEAT + (lj - 2 * FEAT)] = hn;
      hown = hn;
    }
#pragma unroll
    for (int k = 0; k < FEAT; ++k) hrep[k] = __shfl(hown, 2 * FEAT + k);
    if (__all(same)) {  // exact fp32 fixed point -> rest constant
      if (nlane) {
        for (int t2 = t + 1; t2 < TSTEPS; ++t2)
          orow[t2 * FEAT + (lj - 2 * FEAT)] = hn;
      }
      break;
    }
  }
}

extern "C" void kernel_launch(void* const* d_in, const int* in_sizes, int n_in,
                              void* d_out, int out_size, void* d_ws, size_t ws_size,
                              hipStream_t stream) {
  (void)in_sizes; (void)n_in; (void)out_size; (void)d_ws; (void)ws_size;
  const float* x    = (const float*)d_in[0];
  const float* eWih = (const float*)d_in[1];
  const float* eWhh = (const float*)d_in[2];
  const float* ebih = (const float*)d_in[3];
  const float* ebhh = (const float*)d_in[4];
  const float* fcW  = (const float*)d_in[5];
  const float* fcb  = (const float*)d_in[6];
  const float* dWih = (const float*)d_in[7];
  const float* dWhh = (const float*)d_in[8];
  const float* dbih = (const float*)d_in[9];
  const float* dbhh = (const float*)d_in[10];

  hipLaunchKernelGGL(gru_enc, dim3(BATCH / ROWS), dim3(512), 0, stream,
                     x, eWih, eWhh, ebih, ebhh, fcW, fcb, (float*)d_out);
  hipLaunchKernelGGL(gru_dec, dim3(BATCH), dim3(64), 0, stream,
                     dWih, dWhh, dbih, dbhh, (float*)d_out);
}

// Round 3
// 3038.244 us; speedup vs baseline: 1.5335x; 1.1194x over previous
//
#include <hip/hip_runtime.h>
#include <stdint.h>

// GRU acoustic model, fp32 I/O. R12: 16 waves (1024 thr), 1 slice/wave —
// overlap via occupancy. R11 post-mortem: 1-barrier gate-colocated step
// landed 2933us (step 3437 cyc) vs per-SIMD MFMA floor ~1820 cyc. With
// 2 waves/SIMD in lockstep phases, the matrix pipe idles during gate
// tails + LDS reads: overlap-bound, not pipe-bound. R12: same total work,
// 16 waves x 1 register slice (slices 0-15), extra slices 16-18 from LDS
// on waves 0-2 (distinct SIMDs), x-prefetch on wave 15 (SIMD3). 4 waves/
// SIMD interleave MFMA streams with other waves' tails. Register budget
// for the 128-cap (4 w/SIMD): kt=4 Whh chunk in LDS (wl4), JIT A-chunk
// loads, extra-slice Wih/biases in LDS (wxE/ebE). One lgkm barrier/step;
// numerics identical to R9-R11. Decoder unchanged (proven R2-R11).
#define FEAT 13
#define EMB 300
#define BATCH 64
#define TSTEPS 2048
#define ROWS 4              // valid batch rows per WG
#define HSTR 320            // hbuf row stride, bytes (20 granules of 16)
#define QW  2199.7045f      // 127*sqrt(300)
#define SWH 3.5795795e-6f   // 1/(127*127*sqrt(300))

typedef float  floatx4 __attribute__((ext_vector_type(4)));
typedef short  shortx8 __attribute__((ext_vector_type(8)));
typedef int    intx4   __attribute__((ext_vector_type(4)));

__device__ __forceinline__ uint16_t f2b(float f) {
  union { float f; uint32_t i; } c; c.f = f;
  uint32_t r = c.i + 0x7fffu + ((c.i >> 16) & 1u);
  return (uint16_t)(r >> 16);
}
__device__ __forceinline__ float sigf(float x) {
  return __builtin_amdgcn_rcpf(1.f + __expf(-x));
}
__device__ __forceinline__ float tanhf_(float x) {
  return 1.f - 2.f * __builtin_amdgcn_rcpf(1.f + __expf(2.f * x));
}
__device__ __forceinline__ int q8w(float v) {
  return __float2int_rn(fminf(fmaxf(v * QW, -127.f), 127.f));
}

// Raw barrier: LDS-order only (no vmcnt drain; wave 15's global x loads
// stay in flight across it).
__device__ __forceinline__ void barx() {
  asm volatile("s_waitcnt lgkmcnt(0)" ::: "memory");
  __builtin_amdgcn_s_barrier();
  asm volatile("" ::: "memory");
}

#define MFI8(A, B, C) __builtin_amdgcn_mfma_i32_16x16x64_i8(A, B, C, 0, 0, 0)
#define MFBF(A, B, C) __builtin_amdgcn_mfma_f32_16x16x32_bf16(A, B, C, 0, 0, 0)

__launch_bounds__(1024, 4)
__global__ void gru_enc(const float* __restrict__ x,     // [64][2048][13]
                        const float* __restrict__ eWih,  // [900][13]
                        const float* __restrict__ eWhh,  // [900][300]
                        const float* __restrict__ ebih,  // [900]
                        const float* __restrict__ ebhh,  // [900]
                        const float* __restrict__ fcW,   // [300][300]
                        const float* __restrict__ fcb,   // [300]
                        float* __restrict__ out) {
  // hb: element (row r, col c) at byte r*HSTR + (c ^ (r<<4)) (involution;
  // logical pad granule 19 maps to the per-row never-written physical
  // granule -> reads return 0).
  __shared__ __align__(16) signed char hb[2][ROWS][HSTR];     // 2560 B
  __shared__ __align__(16) signed char zsh[16];               // zero granule
  __shared__ __align__(16) uint16_t    xt[2][16][32];         // 2048 B
  __shared__ __align__(16) signed char wl4[16][3][1024];      // 49152 B
  __shared__ __align__(16) signed char wlB[3][3][5][1024];    // 46080 B
  __shared__ __align__(16) uint16_t    wxE[3][3][64][8];      // 9216 B
  __shared__ __align__(16) floatx4     ebE[3][16];            // 768 B

  const int tid = threadIdx.x, lane = tid & 63, w = tid >> 6;   // w in [0,16)
  const int nl = lane & 15, q = lane >> 4;
  const int g = blockIdx.x;          // batch rows 4g..4g+3

  // ---- preamble: own slice w -> regs (kt 0-3) + wl4 (kt 4) ----
  intx4   Bh[3][4];
  shortx8 Bx[3];
  float bS0, bS1, bHN, bIN;
  {
    const int jj = 16 * w + nl;            // <= 255+15 < EMB: always valid
#pragma unroll
    for (int gt = 0; gt < 3; ++gt) {
      const int R = gt * EMB + jj;
      for (int kt = 0; kt < 5; ++kt) {
        int bb[4] = {0, 0, 0, 0};
        for (int e = 0; e < 16; ++e) {
          int kk = kt * 64 + q * 16 + e;
          float v = (kk < EMB) ? eWhh[(size_t)R * EMB + kk] : 0.f;
          bb[e >> 2] |= (q8w(v) & 255) << ((e & 3) * 8);
        }
        intx4 t4; t4[0] = bb[0]; t4[1] = bb[1]; t4[2] = bb[2]; t4[3] = bb[3];
        if (kt < 4) Bh[gt][kt] = t4;
        else        *(intx4*)&wl4[w][gt][lane * 16] = t4;
      }
      union { uint16_t u[8]; shortx8 v; } c;
      for (int e = 0; e < 8; ++e) {
        int kk = q * 8 + e;
        c.u[e] = (kk < FEAT) ? f2b(eWih[R * FEAT + kk]) : (uint16_t)0;
      }
      Bx[gt] = c.v;
    }
    bS0 = ebih[jj] + ebhh[jj];
    bS1 = ebih[EMB + jj] + ebhh[EMB + jj];
    bHN = ebhh[2 * EMB + jj];
    bIN = ebih[2 * EMB + jj];
  }
  // ---- extra slices 16-18: Whh blocks filled by waves 7-15 ----
  if (w >= 7) {
    const int u = w - 7, eI = u / 3, gt = u - 3 * eI;
    const int jj = 16 * (16 + eI) + nl;
    const bool jvv = (jj < EMB);
    const int R = gt * EMB + (jvv ? jj : 0);
    for (int kt = 0; kt < 5; ++kt) {
      int bb[4] = {0, 0, 0, 0};
      for (int e = 0; e < 16; ++e) {
        int kk = kt * 64 + q * 16 + e;
        float v = (jvv && kk < EMB) ? eWhh[(size_t)R * EMB + kk] : 0.f;
        bb[e >> 2] |= (q8w(v) & 255) << ((e & 3) * 8);
      }
      intx4 t4; t4[0] = bb[0]; t4[1] = bb[1]; t4[2] = bb[2]; t4[3] = bb[3];
      *(intx4*)&wlB[eI][gt][kt][lane * 16] = t4;
    }
  }
  // ---- extra slices' Wih fragments (waves 3-5) ----
  if (w >= 3 && w < 6) {
    const int eI = w - 3;
    const int jj = 16 * (16 + eI) + nl;
    const bool jvv = (jj < EMB);
    const int R0 = jvv ? jj : 0;
#pragma unroll
    for (int gt = 0; gt < 3; ++gt) {
      union { uint16_t u[8]; shortx8 v; } c;
      for (int e = 0; e < 8; ++e) {
        int kk = q * 8 + e;
        c.u[e] = (jvv && kk < FEAT)
                     ? f2b(eWih[(size_t)(gt * EMB + R0) * FEAT + kk])
                     : (uint16_t)0;
      }
      *(shortx8*)&wxE[eI][gt][lane][0] = c.v;
    }
  }
  // ---- extra slices' biases (wave 6) ----
  if (w == 6 && lane < 48) {
    const int eI = lane >> 4, j2 = lane & 15;
    const int jj = 16 * (16 + eI) + j2;
    const bool jvv = (jj < EMB);
    floatx4 v;
    v[0] = jvv ? (ebih[jj] + ebhh[jj]) : 0.f;
    v[1] = jvv ? (ebih[EMB + jj] + ebhh[EMB + jj]) : 0.f;
    v[2] = jvv ? ebhh[2 * EMB + jj] : 0.f;
    v[3] = jvv ? ebih[2 * EMB + jj] : 0.f;
    ebE[eI][j2] = v;
  }

  // ---- init LDS: zero h/x buffers + zero granule, then stage x_0 ----
  for (int i = tid; i < 2 * ROWS * HSTR; i += 1024) ((signed char*)hb)[i] = 0;
  if (tid < 16) zsh[tid] = 0;
  for (int i = tid; i < 2 * 16 * 32; i += 1024) ((uint16_t*)xt)[i] = 0;
  __syncthreads();
  if (tid < ROWS * FEAT) {
    int m = tid / FEAT, f = tid - m * FEAT;
    xt[0][4 * m][f] = f2b(x[((size_t)(g * ROWS + m) * TSTEPS) * FEAT + f]);
  }
  __syncthreads();

  // ---- x prefetch pipeline (wave 15, SIMD3) ----
  const bool xl = (w == 15) && (lane < ROWS * FEAT);
  const int xm = lane / FEAT, xf = lane - xm * FEAT;
  const float* xbase = x + ((size_t)(g * ROWS + xm) * TSTEPS) * FEAT + xf;
  float xcur = 0.f;                      // x_t, staged bottom of iter t
  if (xl) xcur = xbase[FEAT];            // x_1
  const float* xnq = xbase + 2 * FEAT;   // next load: x_2

  float hprev = 0.f, hpE = 0.f;
  const int rr_ = nl >> 2;               // A-side batch row (if nl%4==0)
  const bool areal = ((nl & 3) == 0);

  // ================= recurrence: ONE lgkm barrier/step =================
  for (int t = 1; t <= TSTEPS; ++t) {
    const int p = (t - 1) & 1, pn = t & 1;
    float xnxt = 0.f;
    if (xl && t < TSTEPS - 1) { xnxt = *xnq; xnq += FEAT; }

    const signed char* hbp = &hb[p][0][0];
    const shortx8 Ax = *(const shortx8*)&xt[p][nl][q * 8];

    // own slice: 15 MFI8 (kt<4 reg-B, kt=4 LDS-B) + 3 MFBF
    intx4 aR = {0, 0, 0, 0}, aZ = {0, 0, 0, 0}, aN = {0, 0, 0, 0};
#pragma unroll
    for (int kt = 0; kt < 4; ++kt) {
      const int o = kt * 64 + q * 16;
      const signed char* ap =
          areal ? (hbp + rr_ * HSTR + (o ^ (rr_ << 4))) : zsh;
      const intx4 Ahk = *(const intx4*)ap;
      aR = MFI8(Ahk, Bh[0][kt], aR);
      aZ = MFI8(Ahk, Bh[1][kt], aZ);
      aN = MFI8(Ahk, Bh[2][kt], aN);
    }
    {
      const int o = 256 + q * 16;
      const signed char* ap =
          areal ? (hbp + rr_ * HSTR + (o ^ (rr_ << 4))) : zsh;
      const intx4 Ahk = *(const intx4*)ap;
      aR = MFI8(Ahk, *(const intx4*)&wl4[w][0][lane * 16], aR);
      aZ = MFI8(Ahk, *(const intx4*)&wl4[w][1][lane * 16], aZ);
      aN = MFI8(Ahk, *(const intx4*)&wl4[w][2][lane * 16], aN);
    }
    {
      floatx4 zf = {0.f, 0.f, 0.f, 0.f};
      floatx4 xR = MFBF(Ax, Bx[0], zf);
      floatx4 xZ = MFBF(Ax, Bx[1], zf);
      floatx4 xN = MFBF(Ax, Bx[2], zf);
      // reg 0 = (batch row q, col 16w+nl) — gates fully in-register
      float r  = sigf((float)aR[0] * SWH + xR[0] + bS0);
      float z  = sigf((float)aZ[0] * SWH + xZ[0] + bS1);
      float hn = (float)aN[0] * SWH + bHN;
      float n  = tanhf_(xN[0] + bIN + r * hn);
      float h  = z * (hprev - n) + n;
      hprev = h;
      float hq = fminf(fmaxf(h * 127.f, -127.f), 127.f);
      const int c = 16 * w + nl;
      hb[pn][q][c ^ (q << 4)] = (signed char)__float2int_rn(hq);
    }
    if (w < 3) {   // extra slice 16+w, all operands from LDS
      intx4 aR2 = {0, 0, 0, 0}, aZ2 = {0, 0, 0, 0}, aN2 = {0, 0, 0, 0};
#pragma unroll
      for (int kt = 0; kt < 5; ++kt) {
        const int o = kt * 64 + q * 16;
        const signed char* ap =
            areal ? (hbp + rr_ * HSTR + (o ^ (rr_ << 4))) : zsh;
        const intx4 Ahk = *(const intx4*)ap;
        aR2 = MFI8(Ahk, *(const intx4*)&wlB[w][0][kt][lane * 16], aR2);
        aZ2 = MFI8(Ahk, *(const intx4*)&wlB[w][1][kt][lane * 16], aZ2);
        aN2 = MFI8(Ahk, *(const intx4*)&wlB[w][2][kt][lane * 16], aN2);
      }
      floatx4 zf = {0.f, 0.f, 0.f, 0.f};
      floatx4 xR = MFBF(Ax, *(const shortx8*)&wxE[w][0][lane][0], zf);
      floatx4 xZ = MFBF(Ax, *(const shortx8*)&wxE[w][1][lane][0], zf);
      floatx4 xN = MFBF(Ax, *(const shortx8*)&wxE[w][2][lane][0], zf);
      const floatx4 eb = ebE[w][nl];
      float r  = sigf((float)aR2[0] * SWH + xR[0] + eb[0]);
      float z  = sigf((float)aZ2[0] * SWH + xZ[0] + eb[1]);
      float hn = (float)aN2[0] * SWH + eb[2];
      float n  = tanhf_(xN[0] + eb[3] + r * hn);
      float h  = z * (hpE - n) + n;
      hpE = h;
      float hq = fminf(fmaxf(h * 127.f, -127.f), 127.f);
      const int c = 16 * (16 + w) + nl;
      hb[pn][q][c ^ (q << 4)] = (signed char)__float2int_rn(hq);
    }
    // wave 15: stage x_t (loaded last iter -> a full step of vmcnt slack)
    if (xl && t < TSTEPS) xt[pn][4 * xm][xf] = f2b(xcur);

    barx();   // h_t + x_t visible; hb double-buffered
    xcur = xnxt;
  }

  // ================= fc: emb = relu(h_T @ fcW^T + fcb) =================
  {
    float* oemb = out + (size_t)BATCH * TSTEPS * FEAT;
    intx4 AhT[5];
#pragma unroll
    for (int kt = 0; kt < 5; ++kt) {  // T even -> final h in hb[0]
      const int o = kt * 64 + q * 16;
      const signed char* ap =
          areal ? (&hb[0][0][0] + rr_ * HSTR + (o ^ (rr_ << 4))) : zsh;
      AhT[kt] = *(const intx4*)ap;
    }
#pragma unroll
    for (int u = 0; u < 2; ++u) {
      const int s = w + 16 * u;
      if (s < 19) {   // wave-uniform
        const int jj = 16 * s + nl;
        const bool jvv = (jj < EMB);
        intx4 acc = {0, 0, 0, 0};
        for (int kt = 0; kt < 5; ++kt) {
          int bb[4] = {0, 0, 0, 0};
          for (int e = 0; e < 16; ++e) {
            int kk = kt * 64 + q * 16 + e;
            float v = (jvv && kk < EMB) ? fcW[(size_t)jj * EMB + kk] : 0.f;
            bb[e >> 2] |= (q8w(v) & 255) << ((e & 3) * 8);
          }
          intx4 b4; b4[0] = bb[0]; b4[1] = bb[1]; b4[2] = bb[2]; b4[3] = bb[3];
          acc = MFI8(AhT[kt], b4, acc);
        }
        if (jvv) {  // reg 0 = (batch row q, col jj)
          float e2 = (float)acc[0] * SWH + fcb[jj];
          oemb[(size_t)(g * ROWS + q) * EMB + jj] = e2 > 0.f ? e2 : 0.f;
        }
      }
    }
  }
}

// ---------------- decoder: 1 wave per batch, all fp32 (proven) --------------
__launch_bounds__(64, 1)
__global__ void gru_dec(const float* __restrict__ dWih,  // [39][300]
                        const float* __restrict__ dWhh,  // [39][13]
                        const float* __restrict__ dbih,  // [39]
                        const float* __restrict__ dbhh,  // [39]
                        float* __restrict__ out) {
  const int b  = blockIdx.x;
  const int lj = threadIdx.x;            // [0,13)=r [13,26)=z [26,39)=n
  const float* emb = out + (size_t)BATCH * TSTEPS * FEAT + (size_t)b * EMB;

  float Wd[FEAT];
#pragma unroll
  for (int k = 0; k < FEAT; ++k) Wd[k] = 0.f;
  float bhhv = 0.f, dgi = 0.f;
  if (lj < 3 * FEAT) {
#pragma unroll
    for (int k = 0; k < FEAT; ++k) Wd[k] = dWhh[lj * FEAT + k];
    bhhv = dbhh[lj];
    dgi  = dbih[lj];
#pragma unroll 4
    for (int k = 0; k < EMB; ++k)
      dgi = fmaf(emb[k], dWih[lj * EMB + k], dgi);
  }

  float hrep[FEAT];
#pragma unroll
  for (int k = 0; k < FEAT; ++k) hrep[k] = 0.f;
  float hown = 0.f;
  const bool nlane = (lj >= 2 * FEAT && lj < 3 * FEAT);
  float* orow = out + (size_t)b * TSTEPS * FEAT;

  for (int t = 0; t < TSTEPS; ++t) {
    float gh = bhhv;
#pragma unroll
    for (int k = 0; k < FEAT; ++k) gh = fmaf(Wd[k], hrep[k], gh);
    float sg = sigf(dgi + gh);
    float rr = __shfl(sg, (lj - 2 * FEAT) & 63);
    float zz = __shfl(sg, (lj - FEAT) & 63);
    float nn = tanhf_(dgi + rr * gh);
    float hn = zz * (hown - nn) + nn;
    bool same = (!nlane) || (hn == hown);
    if (nlane) {
      orow[t * FEAT + (lj - 2 * FEAT)] = hn;
      hown = hn;
    }
#pragma unroll
    for (int k = 0; k < FEAT; ++k) hrep[k] = __shfl(hown, 2 * FEAT + k);
    if (__all(same)) {  // exact fp32 fixed point -> rest constant
      if (nlane) {
        for (int t2 = t + 1; t2 < TSTEPS; ++t2)
          orow[t2 * FEAT + (lj - 2 * FEAT)] = hn;
      }
      break;
    }
  }
}

extern "C" void kernel_launch(void* const* d_in, const int* in_sizes, int n_in,
                              void* d_out, int out_size, void* d_ws, size_t ws_size,
                              hipStream_t stream) {
  (void)in_sizes; (void)n_in; (void)out_size; (void)d_ws; (void)ws_size;
  const float* x    = (const float*)d_in[0];
  const float* eWih = (const float*)d_in[1];
  const float* eWhh = (const float*)d_in[2];
  const float* ebih = (const float*)d_in[3];
  const float* ebhh = (const float*)d_in[4];
  const float* fcW  = (const float*)d_in[5];
  const float* fcb  = (const float*)d_in[6];
  const float* dWih = (const float*)d_in[7];
  const float* dWhh = (const float*)d_in[8];
  const float* dbih = (const float*)d_in[9];
  const float* dbhh = (const float*)d_in[10];

  hipLaunchKernelGGL(gru_enc, dim3(BATCH / ROWS), dim3(1024), 0, stream,
                     x, eWih, eWhh, ebih, ebhh, fcW, fcb, (float*)d_out);
  hipLaunchKernelGGL(gru_dec, dim3(BATCH), dim3(64), 0, stream,
                     dWih, dWhh, dbih, dbhh, (float*)d_out);
}